// Round 8
// baseline (158.042 us; speedup 1.0000x reference)
//
#include <hip/hip_runtime.h>
#include <cstdint>
#include <cstddef>

#define N_ENT 40000
#define DDIM  128
#define BSZ   1024
#define NJT   313               // ceil(40000/128)
#define CH    5                 // j-tiles per block chunk
#define NGRID 1024              // 64 groups x 16 members (group 63 idle)

typedef short s16x8 __attribute__((ext_vector_type(8)));
typedef float f32x4 __attribute__((ext_vector_type(4)));

// ws layout (bytes), 256-aligned (partials = NGRID floats):
//   0       : partials f32[1024]   (per-block sums; idle blocks write 0)
//   20480   : tpart    f32[1024]
//   24576   : enorm    f32[40000]
//   184576  : cnorm    f32[2048]
//   192768  : c_bf     u16[2048*128]
//   717056  : ent_bf   u16[40000*128]  -> end 10,957,056 B
#define OFF_PART  0
#define OFF_TPART 20480
#define OFF_ENORM 24576
#define OFF_CNORM 184576
#define OFF_CBF   192768
#define OFF_EBF   717056

#define S_CLAMP 15.9423847f      // -ln(2^-23): clip(pred, eps, 1-eps) bound in fp32
#define U_CLAMP 0.159423847f     // S_CLAMP / 100  (s = 100*u)
#define LP_MAX (-1.1920929e-7f)  // ln(fl32(1-1e-7))

__device__ __forceinline__ unsigned short f2bf(float f) {
  uint32_t u = __float_as_uint(f);
  u += 0x7fffu + ((u >> 16) & 1u);   // round-to-nearest-even
  return (unsigned short)(u >> 16);
}

// Skinny prep, float4 width (16 B/lane): unchanged from R15 (verified).
__global__ __launch_bounds__(256) void prep_k(const float* __restrict__ ent,
                                              const int* __restrict__ pos_h,
                                              const int* __restrict__ pos_t,
                                              const int* __restrict__ neg_h,
                                              const float* __restrict__ rpos,
                                              const float* __restrict__ rneg,
                                              const int* __restrict__ l1_flag,
                                              unsigned short* __restrict__ ent_bf,
                                              float* __restrict__ enorm,
                                              unsigned short* __restrict__ c_bf,
                                              float* __restrict__ cnorm,
                                              float* __restrict__ tpart) {
  const int lane = threadIdx.x & 63, wv = threadIdx.x >> 6;
  const int ih = lane >> 5, il = lane & 31;      // half-index, lane-in-half
  const int blk = blockIdx.x;
  if (blk < 5000) {
    int row = blk * 8 + wv * 2 + ih;             // 0..39999
    float4 v = reinterpret_cast<const float4*>(ent + (size_t)row * DDIM)[il];
    ushort4 h4; h4.x = f2bf(v.x); h4.y = f2bf(v.y); h4.z = f2bf(v.z); h4.w = f2bf(v.w);
    reinterpret_cast<ushort4*>(ent_bf + (size_t)row * DDIM)[il] = h4;
    float sq = fmaf(v.x, v.x, fmaf(v.y, v.y, fmaf(v.z, v.z, v.w * v.w)));
    #pragma unroll
    for (int m = 1; m <= 16; m <<= 1) sq += __shfl_xor(sq, m);   // within 32-lane half
    if (il == 0) enorm[row] = sq;
  } else {
    int row = (blk - 5000) * 8 + wv * 2 + ih;    // 0..2047
    int br = row >> 10, i = row & 1023;
    int h = br ? neg_h[i] : pos_h[i];
    const float* rs = br ? rneg : rpos;
    float4 e  = reinterpret_cast<const float4*>(ent + (size_t)h * DDIM)[il];
    float4 rv = reinterpret_cast<const float4*>(rs + (size_t)i * DDIM)[il];
    float c0 = e.x + rv.x, c1 = e.y + rv.y, c2 = e.z + rv.z, c3 = e.w + rv.w;
    ushort4 h4; h4.x = f2bf(c0); h4.y = f2bf(c1); h4.z = f2bf(c2); h4.w = f2bf(c3);
    reinterpret_cast<ushort4*>(c_bf + (size_t)row * DDIM)[il] = h4;
    float sq = fmaf(c0, c0, fmaf(c1, c1, fmaf(c2, c2, c3 * c3)));
    #pragma unroll
    for (int m = 1; m <= 16; m <<= 1) sq += __shfl_xor(sq, m);
    if (il == 0) cnorm[row] = sq;
    if (br == 0) {
      int t = pos_t[i];
      float4 et = reinterpret_cast<const float4*>(ent + (size_t)t * DDIM)[il];
      float d0 = c0 - et.x, d1 = c1 - et.y, d2v = c2 - et.z, d3 = c3 - et.w;
      float d2 = fmaf(d0, d0, fmaf(d1, d1, fmaf(d2v, d2v, d3 * d3)));
      float m1 = fabsf(d0) + fabsf(d1) + fabsf(d2v) + fabsf(d3);
      #pragma unroll
      for (int m = 1; m <= 16; m <<= 1) { d2 += __shfl_xor(d2, m); m1 += __shfl_xor(m1, m); }
      if (il == 0) {
        float s = (*l1_flag) ? (100.f / fmaxf(m1, 1e-12f))
                             : (100.f * rsqrtf(fmaxf(d2, 0.f)));  // d2=0 -> inf, clamps ok
        float x  = __expf(-s);
        float L  = log1pf(x);
        float Bt = fminf(-L, LP_MAX);          // exact log(pred)
        float Ap = fmaxf(-s, -S_CLAMP);        // what main_k adds for this element
        tpart[i] = Bt - Ap;
      }
    }
  }
}

// Main, R19: streaming (R18) + FULL-TILE-DEEP register prefetch. R18 post-
// mortem: no-barrier/no-LDS landed at the same 62 µs — barrier convoy is
// exonerated; the wall is EXPOSED L2 LATENCY (1-deep kc prefetch: ~160-cyc
// MFMA cluster can't cover ~200-cyc loads; 2 waves/SIMD can't fill the gap;
// VALUBusy 43%). R16 won (53.8) because its DMA was issued a full tile
// ahead. Port that scheduling to registers: four fixed-name buffers
// bvk0..bvk3 (one per kc); right after MFMA-kc consumes bvkN, reissue
// bvkN <- kc(t+1). Cover = 3 MFMA clusters + ~320-inst epilogue ~ 1400 cyc
// >> 200-cyc L2 latency. Addressing collapsed to 4 persistent per-lane
// pointers advanced +32KB/tile (8 VALU/tile), kc offsets folded into 64 B
// immediates; the clamped recompute path survives only for the one partial
// tile (block-uniform branch, group 62). Regs ~240 of 512 (avk 64 + bvk 64
// + acc 64 + cnv 16 + misc) -> no spill, 2 waves/SIMD; the win is latency
// hiding, not occupancy. Same element math/masking as R18 (absmax was 0).
__global__ __launch_bounds__(256) void main_k(const unsigned short* __restrict__ c_bf,
                                              const unsigned short* __restrict__ ent_bf,
                                              const float* __restrict__ cnorm,
                                              const float* __restrict__ enorm,
                                              const int* __restrict__ l1_flag,
                                              const int* __restrict__ pos_h,
                                              const int* __restrict__ neg_h,
                                              const float* __restrict__ rpos,
                                              const float* __restrict__ rneg,
                                              const float* __restrict__ ent_f32,
                                              float* __restrict__ partials) {
  __shared__ float s4[4];
  const int id = blockIdx.x;
  const int c8 = id & 7;
  const int q  = id >> 3;
  const int mm = q & 15;                          // member 0..15
  const int gg = q >> 4;                          // 0..7
  const int gp = c8 * 8 + gg;                     // group 0..63
  const int jtB = gp * CH;
  const int tid = threadIdx.x, lane = tid & 63, wv = tid >> 6;
  if (jtB >= NJT) {                               // idle group: zero its partial
    if (tid == 0) partials[id] = 0.f;
    return;
  }
  const int nt = (jtB + CH <= NJT) ? CH : (NJT - jtB);
  const int branch = mm & 1;
  const int i0 = (mm >> 1) * 128;
  const int wm = wv >> 1, wn = wv & 1;            // 2x2 waves, 64x64 each
  const int r15 = lane & 15, quad = lane >> 4;

  // clamped B-fragment load (partial-tile path only; group 62, one tile)
#define LOADC(dst_, j0_, kc_) do {                                             \
    _Pragma("unroll")                                                          \
    for (int tn_ = 0; tn_ < 4; ++tn_) {                                        \
      int jg_ = (j0_) + wn * 64 + tn_ * 16 + r15;                              \
      if (jg_ >= N_ENT) jg_ = N_ENT - 1;                                       \
      dst_[tn_] = *reinterpret_cast<const s16x8*>(                             \
          ent_bf + (size_t)jg_ * DDIM + ((kc_) * 4 + quad) * 8);               \
    }                                                                          \
  } while (0)

  // fast-path B load: persistent pointer + 64B-immediate kc offset
#define LOADP(dst_, kc_) do {                                                  \
    _Pragma("unroll")                                                          \
    for (int tn_ = 0; tn_ < 4; ++tn_)                                          \
      dst_[tn_] = *reinterpret_cast<const s16x8*>(pB[tn_] + (kc_) * 32);       \
  } while (0)

#define MFMA16(kc_, bv_) do {                                                  \
    _Pragma("unroll")                                                          \
    for (int tm_ = 0; tm_ < 4; ++tm_)                                          \
      _Pragma("unroll")                                                        \
      for (int tn_ = 0; tn_ < 4; ++tn_)                                        \
        acc[tm_][tn_] = __builtin_amdgcn_mfma_f32_16x16x32_bf16(               \
            avk[kc_][tm_], bv_[tn_], acc[tm_][tn_], 0, 0, 0);                  \
  } while (0)

  // ---- persistent per-lane pointers (tile 0 is always full for active gp) --
  const unsigned short* pB[4];
  #pragma unroll
  for (int tn = 0; tn < 4; ++tn) {
    int jg = jtB * 128 + wn * 64 + tn * 16 + r15;
    pB[tn] = ent_bf + (size_t)jg * DDIM + quad * 8;
  }
  const float* pE = enorm + jtB * 128 + wn * 64 + r15;

  // ---- A fragments -> registers, ALL kc (live for the whole block) ----
  const unsigned short* Abase = c_bf + ((size_t)(branch << 10) + i0) * DDIM;
  s16x8 avk[4][4];                                // [kc][tm], 64 VGPRs
  #pragma unroll
  for (int tm = 0; tm < 4; ++tm) {
    const unsigned short* ar = Abase + (size_t)(wm * 64 + tm * 16 + r15) * DDIM + quad * 8;
    #pragma unroll
    for (int kc = 0; kc < 4; ++kc)
      avk[kc][tm] = *reinterpret_cast<const s16x8*>(ar + kc * 32);
  }

  float cnv[16];                                  // fixed for the whole block
  #pragma unroll
  for (int tm = 0; tm < 4; ++tm)
    #pragma unroll
    for (int r = 0; r < 4; ++r)
      cnv[tm * 4 + r] = cnorm[(branch << 10) + i0 + wm * 64 + tm * 16 + quad * 4 + r];

  const int l1 = *l1_flag;
  const f32x4 zf = {0.f, 0.f, 0.f, 0.f};

  // ---- prologue: tile-0's four kc buffers in flight ----
  s16x8 bvk0[4], bvk1[4], bvk2[4], bvk3[4];
  LOADP(bvk0, 0); LOADP(bvk1, 1); LOADP(bvk2, 2); LOADP(bvk3, 3);

  float ls0 = 0.f, ls1 = 0.f, ls2 = 0.f, ls3 = 0.f;   // accumulate across tiles

  #pragma unroll 1
  for (int t = 0; t < nt; ++t) {
    const int j0 = (jtB + t) * 128;
    const bool haveNext = (t + 1) < nt;           // block-uniform
    const bool nextPartial = haveNext && (j0 + 256 > N_ENT);   // group 62 only

    // this tile's entity norms (pre-advance); consumed ~1200 cyc later
    float en[4];
    #pragma unroll
    for (int tn = 0; tn < 4; ++tn) en[tn] = pE[tn * 16];

    if (haveNext) {                               // pointers -> tile t+1
      #pragma unroll
      for (int tn = 0; tn < 4; ++tn) pB[tn] += 128 * DDIM;
      pE += 128;
    }

    f32x4 acc[4][4];
    #pragma unroll
    for (int a = 0; a < 4; ++a)
      #pragma unroll
      for (int b = 0; b < 4; ++b) acc[a][b] = zf;

    // kc clusters: consume bvkN, immediately reissue bvkN <- kc N of t+1
    MFMA16(0, bvk0);
    if (haveNext) { if (!nextPartial) LOADP(bvk0, 0); else LOADC(bvk0, j0 + 128, 0); }
    MFMA16(1, bvk1);
    if (haveNext) { if (!nextPartial) LOADP(bvk1, 1); else LOADC(bvk1, j0 + 128, 1); }
    MFMA16(2, bvk2);
    if (haveNext) { if (!nextPartial) LOADP(bvk2, 2); else LOADC(bvk2, j0 + 128, 2); }
    MFMA16(3, bvk3);
    if (haveNext) { if (!nextPartial) LOADP(bvk3, 3); else LOADC(bvk3, j0 + 128, 3); }

    // ---- epilogue: add, fma, rsqrt, fmin, add (u-units), 4 accumulators ----
    const bool full = (j0 + 128) <= N_ENT;        // block-uniform per tile
    if (!l1) {
      #pragma unroll
      for (int tm = 0; tm < 4; ++tm) {
        if (full) {
          #pragma unroll
          for (int tn = 0; tn < 4; ++tn) {
            float e0 = en[tn];
            float u0 = rsqrtf(fmaf(-2.f, acc[tm][tn][0], cnv[tm * 4 + 0] + e0));
            float u1 = rsqrtf(fmaf(-2.f, acc[tm][tn][1], cnv[tm * 4 + 1] + e0));
            float u2 = rsqrtf(fmaf(-2.f, acc[tm][tn][2], cnv[tm * 4 + 2] + e0));
            float u3 = rsqrtf(fmaf(-2.f, acc[tm][tn][3], cnv[tm * 4 + 3] + e0));
            ls0 += fminf(u0, U_CLAMP);            // <=0/NaN -> fmin clamps
            ls1 += fminf(u1, U_CLAMP);
            ls2 += fminf(u2, U_CLAMP);
            ls3 += fminf(u3, U_CLAMP);
          }
        } else {
          #pragma unroll
          for (int tn = 0; tn < 4; ++tn) {
            int jg = j0 + wn * 64 + tn * 16 + r15;
            if (jg < N_ENT) {
              float e0 = en[tn];
              ls0 += fminf(rsqrtf(fmaf(-2.f, acc[tm][tn][0], cnv[tm * 4 + 0] + e0)), U_CLAMP);
              ls1 += fminf(rsqrtf(fmaf(-2.f, acc[tm][tn][1], cnv[tm * 4 + 1] + e0)), U_CLAMP);
              ls2 += fminf(rsqrtf(fmaf(-2.f, acc[tm][tn][2], cnv[tm * 4 + 2] + e0)), U_CLAMP);
              ls3 += fminf(rsqrtf(fmaf(-2.f, acc[tm][tn][3], cnv[tm * 4 + 3] + e0)), U_CLAMP);
            }
          }
        }
      }
    } else {
      // L1 fallback (dead with this harness's inputs): recompute on the fly.
      const float* rs = branch ? rneg : rpos;
      const int*   hb = branch ? neg_h : pos_h;
      #pragma unroll 1
      for (int tm = 0; tm < 4; ++tm) {
        #pragma unroll 1
        for (int r = 0; r < 4; ++r) {
          int bi = i0 + wm * 64 + tm * 16 + quad * 4 + r;
          int hh = hb[bi];
          #pragma unroll 1
          for (int tn = 0; tn < 4; ++tn) {
            int jg = j0 + wn * 64 + tn * 16 + r15;
            if (jg < N_ENT) {
              const float* cp1 = ent_f32 + (size_t)hh * DDIM;
              const float* cp2 = rs + (size_t)bi * DDIM;
              const float* ep  = ent_f32 + (size_t)jg * DDIM;
              float man = 0.f;
              #pragma unroll 1
              for (int d = 0; d < DDIM; ++d) man += fabsf(cp1[d] + cp2[d] - ep[d]);
              float s = 100.f / fmaxf(man, 1e-12f);
              ls0 += 0.01f * fminf(s, S_CLAMP);   // same u-unit scale
            }
          }
        }
      }
    }
  }

  // one reduction per block (the only barrier in the kernel)
  float lsum = (ls0 + ls1) + (ls2 + ls3);
  #pragma unroll
  for (int m = 32; m; m >>= 1) lsum += __shfl_xor(lsum, m);
  if (lane == 0) s4[wv] = lsum;
  __syncthreads();
  if (tid == 0)
    partials[id] = (s4[0] + s4[1]) + (s4[2] + s4[3]);
#undef LOADC
#undef LOADP
#undef MFMA16
}

// Single-block deterministic finalize: 1024 threads; thread i takes block-
// partial i (x 100/(B*N)) + tpart[i] (x -1/(B*N)) in double, block-reduce,
// one plain store. No atomics -> no d_out memset node needed.
__global__ __launch_bounds__(1024) void finalize_k(const float* __restrict__ partials,
                                                   const float* __restrict__ tpart,
                                                   float* __restrict__ out) {
  const int tid = threadIdx.x, lane = tid & 63, wv = tid >> 6;
  const double inv = 1.0 / ((double)BSZ * (double)N_ENT);
  double v = (double)partials[tid] * (100.0 * inv) + (double)tpart[tid] * (-inv);
  #pragma unroll
  for (int m = 32; m; m >>= 1) v += __shfl_xor(v, m);
  __shared__ double sd[16];
  if (lane == 0) sd[wv] = v;
  __syncthreads();
  if (wv == 0) {
    double t = (lane < 16) ? sd[lane] : 0.0;
    #pragma unroll
    for (int m = 8; m; m >>= 1) t += __shfl_xor(t, m);
    if (lane == 0) out[0] = (float)t;
  }
}

extern "C" void kernel_launch(void* const* d_in, const int* in_sizes, int n_in,
                              void* d_out, int out_size, void* d_ws, size_t ws_size,
                              hipStream_t stream) {
  const int*   pos_h = (const int*)d_in[0];
  const int*   pos_t = (const int*)d_in[1];
  const int*   neg_h = (const int*)d_in[2];
  // d_in[3] = neg_t_batch (unused by reference)
  const float* rpos  = (const float*)d_in[4];
  const float* rneg  = (const float*)d_in[5];
  const float* ent   = (const float*)d_in[6];
  const int*   l1    = (const int*)d_in[7];

  char* ws = (char*)d_ws;
  float*          partials = (float*)(ws + OFF_PART);
  float*          tpart    = (float*)(ws + OFF_TPART);
  float*          enorm    = (float*)(ws + OFF_ENORM);
  float*          cnorm    = (float*)(ws + OFF_CNORM);
  unsigned short* c_bf     = (unsigned short*)(ws + OFF_CBF);
  unsigned short* ent_bf   = (unsigned short*)(ws + OFF_EBF);

  prep_k<<<5256, 256, 0, stream>>>(ent, pos_h, pos_t, neg_h, rpos, rneg, l1,
                                   ent_bf, enorm, c_bf, cnorm, tpart);

  main_k<<<NGRID, 256, 0, stream>>>(c_bf, ent_bf, cnorm, enorm, l1,
                                    pos_h, neg_h, rpos, rneg, ent, partials);

  finalize_k<<<1, 1024, 0, stream>>>(partials, tpart, (float*)d_out);
}

// Round 9
// 143.858 us; speedup vs baseline: 1.0986x; 1.0986x over previous
//
#include <hip/hip_runtime.h>
#include <cstdint>
#include <cstddef>

#define N_ENT 40000
#define DDIM  128
#define BSZ   1024
#define NJT   313               // ceil(40000/128)
#define CH    5                 // j-tiles per block chunk
#define NGRID 512               // 64 groups x 8 member-PAIRS (group 63 idle)

#define AS1 __attribute__((address_space(1)))
#define AS3 __attribute__((address_space(3)))

typedef short s16x8 __attribute__((ext_vector_type(8)));
typedef float f32x4 __attribute__((ext_vector_type(4)));

// ws layout (bytes), 256-aligned (partials = NGRID floats):
//   0       : partials f32[512]    (per-block sums; idle blocks write 0)
//   20480   : tpart    f32[1024]
//   24576   : enorm    f32[40000]
//   184576  : cnorm    f32[2048]
//   192768  : c_bf     u16[2048*128]
//   717056  : ent_bf   u16[40000*128]  -> end 10,957,056 B
#define OFF_PART  0
#define OFF_TPART 20480
#define OFF_ENORM 24576
#define OFF_CNORM 184576
#define OFF_CBF   192768
#define OFF_EBF   717056

#define S_CLAMP 15.9423847f      // -ln(2^-23): clip(pred, eps, 1-eps) bound in fp32
#define U_CLAMP 0.159423847f     // S_CLAMP / 100  (s = 100*u)
#define LP_MAX (-1.1920929e-7f)  // ln(fl32(1-1e-7))

__device__ __forceinline__ unsigned short f2bf(float f) {
  uint32_t u = __float_as_uint(f);
  u += 0x7fffu + ((u >> 16) & 1u);   // round-to-nearest-even
  return (unsigned short)(u >> 16);
}

// Skinny prep, float4 width (16 B/lane): unchanged from R15 (verified).
__global__ __launch_bounds__(256) void prep_k(const float* __restrict__ ent,
                                              const int* __restrict__ pos_h,
                                              const int* __restrict__ pos_t,
                                              const int* __restrict__ neg_h,
                                              const float* __restrict__ rpos,
                                              const float* __restrict__ rneg,
                                              const int* __restrict__ l1_flag,
                                              unsigned short* __restrict__ ent_bf,
                                              float* __restrict__ enorm,
                                              unsigned short* __restrict__ c_bf,
                                              float* __restrict__ cnorm,
                                              float* __restrict__ tpart) {
  const int lane = threadIdx.x & 63, wv = threadIdx.x >> 6;
  const int ih = lane >> 5, il = lane & 31;      // half-index, lane-in-half
  const int blk = blockIdx.x;
  if (blk < 5000) {
    int row = blk * 8 + wv * 2 + ih;             // 0..39999
    float4 v = reinterpret_cast<const float4*>(ent + (size_t)row * DDIM)[il];
    ushort4 h4; h4.x = f2bf(v.x); h4.y = f2bf(v.y); h4.z = f2bf(v.z); h4.w = f2bf(v.w);
    reinterpret_cast<ushort4*>(ent_bf + (size_t)row * DDIM)[il] = h4;
    float sq = fmaf(v.x, v.x, fmaf(v.y, v.y, fmaf(v.z, v.z, v.w * v.w)));
    #pragma unroll
    for (int m = 1; m <= 16; m <<= 1) sq += __shfl_xor(sq, m);   // within 32-lane half
    if (il == 0) enorm[row] = sq;
  } else {
    int row = (blk - 5000) * 8 + wv * 2 + ih;    // 0..2047
    int br = row >> 10, i = row & 1023;
    int h = br ? neg_h[i] : pos_h[i];
    const float* rs = br ? rneg : rpos;
    float4 e  = reinterpret_cast<const float4*>(ent + (size_t)h * DDIM)[il];
    float4 rv = reinterpret_cast<const float4*>(rs + (size_t)i * DDIM)[il];
    float c0 = e.x + rv.x, c1 = e.y + rv.y, c2 = e.z + rv.z, c3 = e.w + rv.w;
    ushort4 h4; h4.x = f2bf(c0); h4.y = f2bf(c1); h4.z = f2bf(c2); h4.w = f2bf(c3);
    reinterpret_cast<ushort4*>(c_bf + (size_t)row * DDIM)[il] = h4;
    float sq = fmaf(c0, c0, fmaf(c1, c1, fmaf(c2, c2, c3 * c3)));
    #pragma unroll
    for (int m = 1; m <= 16; m <<= 1) sq += __shfl_xor(sq, m);
    if (il == 0) cnorm[row] = sq;
    if (br == 0) {
      int t = pos_t[i];
      float4 et = reinterpret_cast<const float4*>(ent + (size_t)t * DDIM)[il];
      float d0 = c0 - et.x, d1 = c1 - et.y, d2v = c2 - et.z, d3 = c3 - et.w;
      float d2 = fmaf(d0, d0, fmaf(d1, d1, fmaf(d2v, d2v, d3 * d3)));
      float m1 = fabsf(d0) + fabsf(d1) + fabsf(d2v) + fabsf(d3);
      #pragma unroll
      for (int m = 1; m <= 16; m <<= 1) { d2 += __shfl_xor(d2, m); m1 += __shfl_xor(m1, m); }
      if (il == 0) {
        float s = (*l1_flag) ? (100.f / fmaxf(m1, 1e-12f))
                             : (100.f * rsqrtf(fmaxf(d2, 0.f)));  // d2=0 -> inf, clamps ok
        float x  = __expf(-s);
        float L  = log1pf(x);
        float Bt = fminf(-L, LP_MAX);          // exact log(pred)
        float Ap = fmaxf(-s, -S_CLAMP);        // what main_k adds for this element
        tpart[i] = Bt - Ap;
      }
    }
  }
}

// Main, R20: R16 pipeline + TWO MEMBERS per staged tile -> ONE generation.
// Evidence model (fits R10/R16/R18): wall = generations x per-block-time.
// R16 = 1008 blocks / 512 resident slots (2/CU by 66KB LDS) = 2 generations
// x 27 µs = 54 ✓. Halve block count instead of per-block time: each block
// owns (group, PAIR) and runs BOTH branches of i-tile p against every staged
// B tile. 504 active blocks <= 512 slots -> all co-resident, wall = one
// block's runtime = 5 x (F + 2M) where F+M = 5.4 µs (R16's per-tile wall,
// split unknown — this round measures it). DMA/barrier events per output
// element halve; member1's MFMA/epilogue adds ~1-1.5 µs issue per tile.
// A frags + cnorm streamed per member per tile from L2-hot c_bf (k-loop
// fully unrolled -> compiler hoists/interleaves within register budget;
// NOT forced persistent in source, keeping arch-VGPR under the 2-waves/SIMD
// ceiling — R19 lesson: reg-count cliffs dominate latency tricks).
// Same element math/masking as R16 (absmax 0.0 streak); partials now one
// f32 per block (both members+all tiles accumulated in-wave).
__global__ __launch_bounds__(256) void main_k(const unsigned short* __restrict__ c_bf,
                                              const unsigned short* __restrict__ ent_bf,
                                              const float* __restrict__ cnorm,
                                              const float* __restrict__ enorm,
                                              const int* __restrict__ l1_flag,
                                              const int* __restrict__ pos_h,
                                              const int* __restrict__ neg_h,
                                              const float* __restrict__ rpos,
                                              const float* __restrict__ rneg,
                                              const float* __restrict__ ent_f32,
                                              float* __restrict__ partials) {
  __shared__ unsigned short smem[2][128 * 128];   // 64 KB: double-buffered B tile
  __shared__ float s4[4];
  const int id = blockIdx.x;
  const int c8 = id & 7;
  const int q  = id >> 3;                         // 0..63
  const int p  = q & 7;                           // i-tile (pair) 0..7
  const int gg = q >> 3;                          // 0..7
  const int gp = c8 * 8 + gg;                     // group 0..63
  const int jtB = gp * CH;
  const int tid = threadIdx.x, lane = tid & 63, wv = tid >> 6;
  if (jtB >= NJT) {                               // idle group: zero its partial
    if (tid == 0) partials[id] = 0.f;
    return;
  }
  const int nt = (jtB + CH <= NJT) ? CH : (NJT - jtB);
  const int i0 = p * 128;
  const int wm = wv >> 1, wn = wv & 1;            // 2x2 waves, 64x64 each
  const int r15 = lane & 15, quad = lane >> 4;

  // async stage of one 128x128 B tile into buffer `par`, swizzle c'=c^(row&15)
#define STAGE(par_, j0_) do {                                                  \
    _Pragma("unroll")                                                          \
    for (int i_ = 0; i_ < 8; ++i_) {                                           \
      int g_  = i_ * 256 + tid;     /* LDS dst = uniform base + lane*16 */     \
      int r_  = g_ >> 4;                                                       \
      int c_  = (g_ & 15) ^ (r_ & 15);                                         \
      int jr_ = (j0_) + r_; if (jr_ >= N_ENT) jr_ = N_ENT - 1;                 \
      const unsigned short* src_ = ent_bf + (size_t)jr_ * DDIM + c_ * 8;       \
      __builtin_amdgcn_global_load_lds((const AS1 void*)src_,                  \
          (AS3 void*)(&smem[par_][g_ * 8]), 16, 0, 0);                         \
    }                                                                          \
  } while (0)

  STAGE(0, jtB * 128);                            // tile 0 DMA in flight

  const int l1 = *l1_flag;
  const f32x4 zf = {0.f, 0.f, 0.f, 0.f};
  float ls0 = 0.f, ls1 = 0.f, ls2 = 0.f, ls3 = 0.f;   // accumulate everything

  __syncthreads();   // drains vmcnt: tile-0 B staged

  #pragma unroll 1
  for (int t = 0; t < nt; ++t) {
    const int j0  = (jtB + t) * 128;
    const int par = t & 1;
    const bool haveNext = (t + 1) < nt;           // block-uniform

    // issue next tile's DMA NOW — drained by the barrier after BOTH members
    if (haveNext) STAGE(par ^ 1, j0 + 128);

    float en[4];                                  // this tile's entity norms
    #pragma unroll
    for (int tn = 0; tn < 4; ++tn) {
      int jg = j0 + wn * 64 + tn * 16 + r15;
      en[tn] = enorm[jg < N_ENT ? jg : N_ENT - 1];
    }
    const bool full = (j0 + 128) <= N_ENT;        // block-uniform per tile

    #pragma unroll   // k = member/branch, fully unrolled straightline
    for (int k = 0; k < 2; ++k) {
      // A frags + cnorm for this member (L2/L1-hot; compiler hoists if regs allow)
      const unsigned short* Ab = c_bf + ((size_t)(k << 10) + i0) * DDIM;
      s16x8 av[4][4];                             // [kc][tm]
      #pragma unroll
      for (int tm = 0; tm < 4; ++tm) {
        const unsigned short* ar = Ab + (size_t)(wm * 64 + tm * 16 + r15) * DDIM + quad * 8;
        #pragma unroll
        for (int kc = 0; kc < 4; ++kc)
          av[kc][tm] = *reinterpret_cast<const s16x8*>(ar + kc * 32);
      }
      float cnvA[16];
      #pragma unroll
      for (int tm = 0; tm < 4; ++tm)
        #pragma unroll
        for (int r = 0; r < 4; ++r)
          cnvA[tm * 4 + r] = cnorm[(k << 10) + i0 + wm * 64 + tm * 16 + quad * 4 + r];

      f32x4 acc[4][4];
      #pragma unroll
      for (int a = 0; a < 4; ++a)
        #pragma unroll
        for (int b = 0; b < 4; ++b) acc[a][b] = zf;

      #pragma unroll
      for (int kc = 0; kc < 4; ++kc) {
        s16x8 bv[4];
        #pragma unroll
        for (int tn = 0; tn < 4; ++tn) {
          int R  = wn * 64 + tn * 16 + r15;
          int cs = (kc * 4 + quad) ^ r15;
          bv[tn] = *reinterpret_cast<const s16x8*>(&smem[par][R * 128 + cs * 8]);
        }
        #pragma unroll
        for (int tm = 0; tm < 4; ++tm)
          #pragma unroll
          for (int tn = 0; tn < 4; ++tn)
            acc[tm][tn] = __builtin_amdgcn_mfma_f32_16x16x32_bf16(av[kc][tm], bv[tn], acc[tm][tn], 0, 0, 0);
      }

      // ---- epilogue: add, fma, rsqrt, fmin, add (u-units), 4 accumulators ----
      if (!l1) {
        #pragma unroll
        for (int tm = 0; tm < 4; ++tm) {
          if (full) {
            #pragma unroll
            for (int tn = 0; tn < 4; ++tn) {
              float e0 = en[tn];
              float u0 = rsqrtf(fmaf(-2.f, acc[tm][tn][0], cnvA[tm * 4 + 0] + e0));
              float u1 = rsqrtf(fmaf(-2.f, acc[tm][tn][1], cnvA[tm * 4 + 1] + e0));
              float u2 = rsqrtf(fmaf(-2.f, acc[tm][tn][2], cnvA[tm * 4 + 2] + e0));
              float u3 = rsqrtf(fmaf(-2.f, acc[tm][tn][3], cnvA[tm * 4 + 3] + e0));
              ls0 += fminf(u0, U_CLAMP);          // <=0/NaN -> fmin clamps
              ls1 += fminf(u1, U_CLAMP);
              ls2 += fminf(u2, U_CLAMP);
              ls3 += fminf(u3, U_CLAMP);
            }
          } else {
            #pragma unroll
            for (int tn = 0; tn < 4; ++tn) {
              int jg = j0 + wn * 64 + tn * 16 + r15;
              if (jg < N_ENT) {
                float e0 = en[tn];
                ls0 += fminf(rsqrtf(fmaf(-2.f, acc[tm][tn][0], cnvA[tm * 4 + 0] + e0)), U_CLAMP);
                ls1 += fminf(rsqrtf(fmaf(-2.f, acc[tm][tn][1], cnvA[tm * 4 + 1] + e0)), U_CLAMP);
                ls2 += fminf(rsqrtf(fmaf(-2.f, acc[tm][tn][2], cnvA[tm * 4 + 2] + e0)), U_CLAMP);
                ls3 += fminf(rsqrtf(fmaf(-2.f, acc[tm][tn][3], cnvA[tm * 4 + 3] + e0)), U_CLAMP);
              }
            }
          }
        }
      } else {
        // L1 fallback (dead with this harness's inputs): recompute on the fly.
        const float* rs = k ? rneg : rpos;
        const int*   hb = k ? neg_h : pos_h;
        #pragma unroll 1
        for (int tm = 0; tm < 4; ++tm) {
          #pragma unroll 1
          for (int r = 0; r < 4; ++r) {
            int bi = i0 + wm * 64 + tm * 16 + quad * 4 + r;
            int hh = hb[bi];
            #pragma unroll 1
            for (int tn = 0; tn < 4; ++tn) {
              int jg = j0 + wn * 64 + tn * 16 + r15;
              if (jg < N_ENT) {
                const float* cp1 = ent_f32 + (size_t)hh * DDIM;
                const float* cp2 = rs + (size_t)bi * DDIM;
                const float* ep  = ent_f32 + (size_t)jg * DDIM;
                float man = 0.f;
                #pragma unroll 1
                for (int d = 0; d < DDIM; ++d) man += fabsf(cp1[d] + cp2[d] - ep[d]);
                float s = 100.f / fmaxf(man, 1e-12f);
                ls0 += 0.01f * fminf(s, S_CLAMP); // same u-unit scale
              }
            }
          }
        }
      }
    }   // member loop

    __syncthreads();   // drains stage(t+1) — issued two member-phases ago
  }

  // one reduction per block
  float lsum = (ls0 + ls1) + (ls2 + ls3);
  #pragma unroll
  for (int m = 32; m; m >>= 1) lsum += __shfl_xor(lsum, m);
  if (lane == 0) s4[wv] = lsum;
  __syncthreads();
  if (tid == 0)
    partials[id] = (s4[0] + s4[1]) + (s4[2] + s4[3]);
#undef STAGE
}

// Single-block deterministic finalize: 1024 threads; thread i<512 takes
// block-partial i (x 100/(B*N)); every thread adds tpart[i] (x -1/(B*N));
// double block-reduce, one plain store. No atomics -> no d_out memset.
__global__ __launch_bounds__(1024) void finalize_k(const float* __restrict__ partials,
                                                   const float* __restrict__ tpart,
                                                   float* __restrict__ out) {
  const int tid = threadIdx.x, lane = tid & 63, wv = tid >> 6;
  const double inv = 1.0 / ((double)BSZ * (double)N_ENT);
  double v = (double)tpart[tid] * (-inv);
  if (tid < NGRID) v += (double)partials[tid] * (100.0 * inv);
  #pragma unroll
  for (int m = 32; m; m >>= 1) v += __shfl_xor(v, m);
  __shared__ double sd[16];
  if (lane == 0) sd[wv] = v;
  __syncthreads();
  if (wv == 0) {
    double t = (lane < 16) ? sd[lane] : 0.0;
    #pragma unroll
    for (int m = 8; m; m >>= 1) t += __shfl_xor(t, m);
    if (lane == 0) out[0] = (float)t;
  }
}

extern "C" void kernel_launch(void* const* d_in, const int* in_sizes, int n_in,
                              void* d_out, int out_size, void* d_ws, size_t ws_size,
                              hipStream_t stream) {
  const int*   pos_h = (const int*)d_in[0];
  const int*   pos_t = (const int*)d_in[1];
  const int*   neg_h = (const int*)d_in[2];
  // d_in[3] = neg_t_batch (unused by reference)
  const float* rpos  = (const float*)d_in[4];
  const float* rneg  = (const float*)d_in[5];
  const float* ent   = (const float*)d_in[6];
  const int*   l1    = (const int*)d_in[7];

  char* ws = (char*)d_ws;
  float*          partials = (float*)(ws + OFF_PART);
  float*          tpart    = (float*)(ws + OFF_TPART);
  float*          enorm    = (float*)(ws + OFF_ENORM);
  float*          cnorm    = (float*)(ws + OFF_CNORM);
  unsigned short* c_bf     = (unsigned short*)(ws + OFF_CBF);
  unsigned short* ent_bf   = (unsigned short*)(ws + OFF_EBF);

  prep_k<<<5256, 256, 0, stream>>>(ent, pos_h, pos_t, neg_h, rpos, rneg, l1,
                                   ent_bf, enorm, c_bf, cnorm, tpart);

  main_k<<<NGRID, 256, 0, stream>>>(c_bf, ent_bf, cnorm, enorm, l1,
                                    pos_h, neg_h, rpos, rneg, ent, partials);

  finalize_k<<<1, 1024, 0, stream>>>(partials, tpart, (float*)d_out);
}

// Round 10
// 125.324 us; speedup vs baseline: 1.2611x; 1.1479x over previous
//
#include <hip/hip_runtime.h>
#include <cstdint>
#include <cstddef>

#define N_ENT 40000
#define DDIM  128
#define BSZ   1024
#define NJT   313               // ceil(40000/128)
#define NPART (16 * NJT)        // 5008 written partials
#define CH    5                 // j-tiles per block chunk
#define NGRID 1024              // 64 groups x 16 members (group 63 idle)

#define AS1 __attribute__((address_space(1)))
#define AS3 __attribute__((address_space(3)))

typedef short s16x8 __attribute__((ext_vector_type(8)));
typedef float f32x4 __attribute__((ext_vector_type(4)));

// Fast hardware rsqrt: single v_rsq_f32 (~1 ulp). R21's one change: default
// rsqrtf() lowers through __ocml_rsqrt_f32 (correctly-rounded multi-inst
// sequence); at 82M epilogue elements that expansion was ~14 µs of hidden
// VALU time (measured VALU-busy ~26 µs vs ~12 µs hand-count of the source).
// Clamp semantics preserved: x=0 -> +inf -> fmin clamps; x<0 -> NaN ->
// v_min_f32 returns the non-NaN operand (U_CLAMP).
__device__ __forceinline__ float frsq(float x) { return __builtin_amdgcn_rsqf(x); }

// ws layout (bytes), 256-aligned:
//   0       : partials f32[5008]
//   20480   : tpart    f32[1024]
//   24576   : enorm    f32[40000]
//   184576  : cnorm    f32[2048]
//   192768  : c_bf     u16[2048*128]
//   717056  : ent_bf   u16[40000*128]  -> end 10,957,056 B
#define OFF_PART  0
#define OFF_TPART 20480
#define OFF_ENORM 24576
#define OFF_CNORM 184576
#define OFF_CBF   192768
#define OFF_EBF   717056

#define S_CLAMP 15.9423847f      // -ln(2^-23): clip(pred, eps, 1-eps) bound in fp32
#define U_CLAMP 0.159423847f     // S_CLAMP / 100  (s = 100*u)
#define LP_MAX (-1.1920929e-7f)  // ln(fl32(1-1e-7))

__device__ __forceinline__ unsigned short f2bf(float f) {
  uint32_t u = __float_as_uint(f);
  u += 0x7fffu + ((u >> 16) & 1u);   // round-to-nearest-even
  return (unsigned short)(u >> 16);
}

// Skinny prep, float4 width (16 B/lane): unchanged from R15 (verified).
// (rsqrtf kept here: 2048 calls, not on the critical path; tpart must match
// the established numerics exactly.)
__global__ __launch_bounds__(256) void prep_k(const float* __restrict__ ent,
                                              const int* __restrict__ pos_h,
                                              const int* __restrict__ pos_t,
                                              const int* __restrict__ neg_h,
                                              const float* __restrict__ rpos,
                                              const float* __restrict__ rneg,
                                              const int* __restrict__ l1_flag,
                                              unsigned short* __restrict__ ent_bf,
                                              float* __restrict__ enorm,
                                              unsigned short* __restrict__ c_bf,
                                              float* __restrict__ cnorm,
                                              float* __restrict__ tpart) {
  const int lane = threadIdx.x & 63, wv = threadIdx.x >> 6;
  const int ih = lane >> 5, il = lane & 31;      // half-index, lane-in-half
  const int blk = blockIdx.x;
  if (blk < 5000) {
    int row = blk * 8 + wv * 2 + ih;             // 0..39999
    float4 v = reinterpret_cast<const float4*>(ent + (size_t)row * DDIM)[il];
    ushort4 h4; h4.x = f2bf(v.x); h4.y = f2bf(v.y); h4.z = f2bf(v.z); h4.w = f2bf(v.w);
    reinterpret_cast<ushort4*>(ent_bf + (size_t)row * DDIM)[il] = h4;
    float sq = fmaf(v.x, v.x, fmaf(v.y, v.y, fmaf(v.z, v.z, v.w * v.w)));
    #pragma unroll
    for (int m = 1; m <= 16; m <<= 1) sq += __shfl_xor(sq, m);   // within 32-lane half
    if (il == 0) enorm[row] = sq;
  } else {
    int row = (blk - 5000) * 8 + wv * 2 + ih;    // 0..2047
    int br = row >> 10, i = row & 1023;
    int h = br ? neg_h[i] : pos_h[i];
    const float* rs = br ? rneg : rpos;
    float4 e  = reinterpret_cast<const float4*>(ent + (size_t)h * DDIM)[il];
    float4 rv = reinterpret_cast<const float4*>(rs + (size_t)i * DDIM)[il];
    float c0 = e.x + rv.x, c1 = e.y + rv.y, c2 = e.z + rv.z, c3 = e.w + rv.w;
    ushort4 h4; h4.x = f2bf(c0); h4.y = f2bf(c1); h4.z = f2bf(c2); h4.w = f2bf(c3);
    reinterpret_cast<ushort4*>(c_bf + (size_t)row * DDIM)[il] = h4;
    float sq = fmaf(c0, c0, fmaf(c1, c1, fmaf(c2, c2, c3 * c3)));
    #pragma unroll
    for (int m = 1; m <= 16; m <<= 1) sq += __shfl_xor(sq, m);
    if (il == 0) cnorm[row] = sq;
    if (br == 0) {
      int t = pos_t[i];
      float4 et = reinterpret_cast<const float4*>(ent + (size_t)t * DDIM)[il];
      float d0 = c0 - et.x, d1 = c1 - et.y, d2v = c2 - et.z, d3 = c3 - et.w;
      float d2 = fmaf(d0, d0, fmaf(d1, d1, fmaf(d2v, d2v, d3 * d3)));
      float m1 = fabsf(d0) + fabsf(d1) + fabsf(d2v) + fabsf(d3);
      #pragma unroll
      for (int m = 1; m <= 16; m <<= 1) { d2 += __shfl_xor(d2, m); m1 += __shfl_xor(m1, m); }
      if (il == 0) {
        float s = (*l1_flag) ? (100.f / fmaxf(m1, 1e-12f))
                             : (100.f * rsqrtf(fmaxf(d2, 0.f)));  // d2=0 -> inf, clamps ok
        float x  = __expf(-s);
        float L  = log1pf(x);
        float Bt = fminf(-L, LP_MAX);          // exact log(pred)
        float Ap = fmaxf(-s, -S_CLAMP);        // what main_k adds for this element
        tpart[i] = Bt - Ap;
      }
    }
  }
}

// Main, R21: R16 structure VERBATIM (best measured: 53.8 µs) with ONE change:
// rsqrtf -> frsq (raw v_rsq_f32). R20's falsification run proved the kernel
// is VALU-issue-bound (one generation, no barrier/LDS dependence, VALU-busy
// ~26 µs across ALL structures vs ~12 µs source hand-count); the excess is
// the OCML correctly-rounded rsqrt expansion at 82M elements. Structure
// unchanged from R16: per-block (group,member), 5-tile chunk, dbuf LDS B
// tile, STAGE(t+1) issued a full tile-compute before its draining barrier,
// A frags register-resident, __launch_bounds__(256,2) (128-VGPR point).
__global__ __launch_bounds__(256, 2) void main_k(const unsigned short* __restrict__ c_bf,
                                                 const unsigned short* __restrict__ ent_bf,
                                                 const float* __restrict__ cnorm,
                                                 const float* __restrict__ enorm,
                                                 const int* __restrict__ l1_flag,
                                                 const int* __restrict__ pos_h,
                                                 const int* __restrict__ neg_h,
                                                 const float* __restrict__ rpos,
                                                 const float* __restrict__ rneg,
                                                 const float* __restrict__ ent_f32,
                                                 float* __restrict__ partials) {
  __shared__ unsigned short smem[2][128 * 128];   // 64 KB: double-buffered B tile
  __shared__ float s4[2][4];                      // [buffer parity][wave]
  const int id = blockIdx.x;
  const int c8 = id & 7;
  const int q  = id >> 3;
  const int mm = q & 15;                          // member 0..15
  const int gg = q >> 4;                          // 0..7
  const int gp = c8 * 8 + gg;                     // group 0..63
  const int jtB = gp * CH;
  if (jtB >= NJT) return;                         // block-uniform, pre-barrier
  const int nt = (jtB + CH <= NJT) ? CH : (NJT - jtB);
  const int branch = mm & 1;
  const int i0 = (mm >> 1) * 128;
  const int tid = threadIdx.x, lane = tid & 63, wv = tid >> 6;
  const int wm = wv >> 1, wn = wv & 1;
  const int r15 = lane & 15, quad = lane >> 4;

  // async stage of one 128x128 B tile into buffer `par`, swizzle c'=c^(row&15)
#define STAGE(par_, j0_) do {                                                  \
    _Pragma("unroll")                                                          \
    for (int i_ = 0; i_ < 8; ++i_) {                                           \
      int g_  = i_ * 256 + tid;     /* LDS dst = uniform base + lane*16 */     \
      int r_  = g_ >> 4;                                                       \
      int c_  = (g_ & 15) ^ (r_ & 15);                                         \
      int jr_ = (j0_) + r_; if (jr_ >= N_ENT) jr_ = N_ENT - 1;                 \
      const unsigned short* src_ = ent_bf + (size_t)jr_ * DDIM + c_ * 8;       \
      __builtin_amdgcn_global_load_lds((const AS1 void*)src_,                  \
          (AS3 void*)(&smem[par_][g_ * 8]), 16, 0, 0);                         \
    }                                                                          \
  } while (0)

  STAGE(0, jtB * 128);                            // tile 0 DMA in flight

  // ---- A fragments -> registers, ALL kc (stay live for the whole block) ----
  const unsigned short* Abase = c_bf + ((size_t)(branch << 10) + i0) * DDIM;
  s16x8 avk[4][4];                                // [kc][tm], 64 VGPRs
  #pragma unroll
  for (int tm = 0; tm < 4; ++tm) {
    const unsigned short* ar = Abase + (size_t)(wm * 64 + tm * 16 + r15) * DDIM + quad * 8;
    #pragma unroll
    for (int kc = 0; kc < 4; ++kc)
      avk[kc][tm] = *reinterpret_cast<const s16x8*>(ar + kc * 32);
  }

  float cnv[16];                                  // fixed for the whole block
  #pragma unroll
  for (int tm = 0; tm < 4; ++tm)
    #pragma unroll
    for (int r = 0; r < 4; ++r)
      cnv[tm * 4 + r] = cnorm[(branch << 10) + i0 + wm * 64 + tm * 16 + quad * 4 + r];

  float en[4];                                    // tile-0 entity norms
  #pragma unroll
  for (int tn = 0; tn < 4; ++tn) {
    int jg = jtB * 128 + wn * 64 + tn * 16 + r15;
    en[tn] = enorm[jg < N_ENT ? jg : N_ENT - 1];
  }

  const int l1 = *l1_flag;
  const f32x4 zf = {0.f, 0.f, 0.f, 0.f};

  __syncthreads();   // drains vmcnt: tile-0 B staged; A/cnv/en landed

  #pragma unroll 1
  for (int t = 0; t < nt; ++t) {
    const int jt  = jtB + t;
    const int j0  = jt * 128;
    const int par = t & 1;
    const bool haveNext = (t + 1) < nt;           // block-uniform

    // issue next tile's DMA NOW — its drain is ~1.7K cycles away (post-compute)
    if (haveNext) STAGE(par ^ 1, j0 + 128);

    float enx[4];                                 // prefetch next tile's norms
    if (haveNext) {
      #pragma unroll
      for (int tn = 0; tn < 4; ++tn) {
        int jg = j0 + 128 + wn * 64 + tn * 16 + r15;
        enx[tn] = enorm[jg < N_ENT ? jg : N_ENT - 1];
      }
    }

    f32x4 acc[4][4];
    #pragma unroll
    for (int a = 0; a < 4; ++a)
      #pragma unroll
      for (int b = 0; b < 4; ++b) acc[a][b] = zf;

    #pragma unroll
    for (int kc = 0; kc < 4; ++kc) {
      s16x8 bv[4];
      #pragma unroll
      for (int tn = 0; tn < 4; ++tn) {
        int R  = wn * 64 + tn * 16 + r15;
        int cs = (kc * 4 + quad) ^ r15;
        bv[tn] = *reinterpret_cast<const s16x8*>(&smem[par][R * 128 + cs * 8]);
      }
      #pragma unroll
      for (int tm = 0; tm < 4; ++tm)
        #pragma unroll
        for (int tn = 0; tn < 4; ++tn)
          acc[tm][tn] = __builtin_amdgcn_mfma_f32_16x16x32_bf16(avk[kc][tm], bv[tn], acc[tm][tn], 0, 0, 0);
    }

    // ---- epilogue: add, fma, v_rsq, fmin, add (u-units), 4 accumulators ----
    const bool full = (j0 + 128) <= N_ENT;        // block-uniform per tile
    float ls0 = 0.f, ls1 = 0.f, ls2 = 0.f, ls3 = 0.f;
    if (!l1) {
      #pragma unroll
      for (int tm = 0; tm < 4; ++tm) {
        if (full) {
          #pragma unroll
          for (int tn = 0; tn < 4; ++tn) {
            float e0 = en[tn];
            float u0 = frsq(fmaf(-2.f, acc[tm][tn][0], cnv[tm * 4 + 0] + e0));
            float u1 = frsq(fmaf(-2.f, acc[tm][tn][1], cnv[tm * 4 + 1] + e0));
            float u2 = frsq(fmaf(-2.f, acc[tm][tn][2], cnv[tm * 4 + 2] + e0));
            float u3 = frsq(fmaf(-2.f, acc[tm][tn][3], cnv[tm * 4 + 3] + e0));
            ls0 += fminf(u0, U_CLAMP);            // <=0/NaN -> fmin clamps
            ls1 += fminf(u1, U_CLAMP);
            ls2 += fminf(u2, U_CLAMP);
            ls3 += fminf(u3, U_CLAMP);
          }
        } else {
          #pragma unroll
          for (int tn = 0; tn < 4; ++tn) {
            int jg = j0 + wn * 64 + tn * 16 + r15;
            if (jg < N_ENT) {
              float e0 = en[tn];
              ls0 += fminf(frsq(fmaf(-2.f, acc[tm][tn][0], cnv[tm * 4 + 0] + e0)), U_CLAMP);
              ls1 += fminf(frsq(fmaf(-2.f, acc[tm][tn][1], cnv[tm * 4 + 1] + e0)), U_CLAMP);
              ls2 += fminf(frsq(fmaf(-2.f, acc[tm][tn][2], cnv[tm * 4 + 2] + e0)), U_CLAMP);
              ls3 += fminf(frsq(fmaf(-2.f, acc[tm][tn][3], cnv[tm * 4 + 3] + e0)), U_CLAMP);
            }
          }
        }
      }
    } else {
      // L1 fallback (dead with this harness's inputs): recompute on the fly.
      const float* rs = branch ? rneg : rpos;
      const int*   hb = branch ? neg_h : pos_h;
      #pragma unroll 1
      for (int tm = 0; tm < 4; ++tm) {
        #pragma unroll 1
        for (int r = 0; r < 4; ++r) {
          int bi = i0 + wm * 64 + tm * 16 + quad * 4 + r;
          int hh = hb[bi];
          #pragma unroll 1
          for (int tn = 0; tn < 4; ++tn) {
            int jg = j0 + wn * 64 + tn * 16 + r15;
            if (jg < N_ENT) {
              const float* cp1 = ent_f32 + (size_t)hh * DDIM;
              const float* cp2 = rs + (size_t)bi * DDIM;
              const float* ep  = ent_f32 + (size_t)jg * DDIM;
              float man = 0.f;
              #pragma unroll 1
              for (int d = 0; d < DDIM; ++d) man += fabsf(cp1[d] + cp2[d] - ep[d]);
              float s = 100.f / fmaxf(man, 1e-12f);
              ls0 += 0.01f * fminf(s, S_CLAMP);   // same u-unit scale
            }
          }
        }
      }
    }
    float lsum = (ls0 + ls1) + (ls2 + ls3);

    #pragma unroll
    for (int m = 32; m; m >>= 1) lsum += __shfl_xor(lsum, m);
    if (lane == 0) s4[par][wv] = lsum;

    if (haveNext) {                               // rotate prefetched norms
      #pragma unroll
      for (int tn = 0; tn < 4; ++tn) en[tn] = enx[tn];
    }

    __syncthreads();   // drains stage(t+1) — issued ~1.7K cycles ago; s4 visible
    if (tid == 0)      // store overlaps next tile's compute; s4[par] safe until t+2
      partials[jt * 16 + mm] = s4[par][0] + s4[par][1] + s4[par][2] + s4[par][3];
  }
#undef STAGE
}

// Single-block deterministic finalize: 1024 threads; each sums ~5 partials
// (x 100/(B*N)) + its tpart element (x -1/(B*N)) in double, block-reduce,
// one plain store. No atomics -> no d_out memset node needed.
__global__ __launch_bounds__(1024) void finalize_k(const float* __restrict__ partials,
                                                   const float* __restrict__ tpart,
                                                   float* __restrict__ out) {
  const int tid = threadIdx.x, lane = tid & 63, wv = tid >> 6;
  const double inv = 1.0 / ((double)BSZ * (double)N_ENT);
  double v = 0.0;
  for (int i = tid; i < NPART; i += 1024) v += (double)partials[i] * (100.0 * inv);
  v += (double)tpart[tid] * (-inv);
  #pragma unroll
  for (int m = 32; m; m >>= 1) v += __shfl_xor(v, m);
  __shared__ double sd[16];
  if (lane == 0) sd[wv] = v;
  __syncthreads();
  if (wv == 0) {
    double t = (lane < 16) ? sd[lane] : 0.0;
    #pragma unroll
    for (int m = 8; m; m >>= 1) t += __shfl_xor(t, m);
    if (lane == 0) out[0] = (float)t;
  }
}

extern "C" void kernel_launch(void* const* d_in, const int* in_sizes, int n_in,
                              void* d_out, int out_size, void* d_ws, size_t ws_size,
                              hipStream_t stream) {
  const int*   pos_h = (const int*)d_in[0];
  const int*   pos_t = (const int*)d_in[1];
  const int*   neg_h = (const int*)d_in[2];
  // d_in[3] = neg_t_batch (unused by reference)
  const float* rpos  = (const float*)d_in[4];
  const float* rneg  = (const float*)d_in[5];
  const float* ent   = (const float*)d_in[6];
  const int*   l1    = (const int*)d_in[7];

  char* ws = (char*)d_ws;
  float*          partials = (float*)(ws + OFF_PART);
  float*          tpart    = (float*)(ws + OFF_TPART);
  float*          enorm    = (float*)(ws + OFF_ENORM);
  float*          cnorm    = (float*)(ws + OFF_CNORM);
  unsigned short* c_bf     = (unsigned short*)(ws + OFF_CBF);
  unsigned short* ent_bf   = (unsigned short*)(ws + OFF_EBF);

  prep_k<<<5256, 256, 0, stream>>>(ent, pos_h, pos_t, neg_h, rpos, rneg, l1,
                                   ent_bf, enorm, c_bf, cnorm, tpart);

  main_k<<<NGRID, 256, 0, stream>>>(c_bf, ent_bf, cnorm, enorm, l1,
                                    pos_h, neg_h, rpos, rneg, ent, partials);

  finalize_k<<<1, 1024, 0, stream>>>(partials, tpart, (float*)d_out);
}